// Round 9
// baseline (300.098 us; speedup 1.0000x reference)
//
#include <hip/hip_runtime.h>
#include <hip/hip_bf16.h>
#include <math.h>

// S=4096, D=2048. out = causal_softmax((xWq^T)(xWk^T)^T / sqrt(D)) @ (xWv^T)
// R9: work-side rebalance. gemm_core identical to R8 (verified). Changes:
//  - vt_qkt: persistent queue, 438 jobs (206 full 32u; rows 12..15 as 232
//    8u K-chunks atomicAdd into zeroed sc rows 3072+).
//  - pv: persistent queue, 320 jobs (K-pieces <=16u; bm>=4 atomicAdd into
//    zeroed out rows 1024+; bm<4 plain write). aux/add pass removed.
//  - cvt merged into one launch. proj_qk unchanged (control).

typedef __attribute__((ext_vector_type(8))) short bf16x8;
typedef __attribute__((ext_vector_type(4))) float f32x4;
typedef __attribute__((ext_vector_type(8))) unsigned short u16x8;
typedef __attribute__((ext_vector_type(4))) int iv4;

__device__ __forceinline__ unsigned short f2bf(float f) {
  unsigned int u = __float_as_uint(f);
  u += 0x7FFFu + ((u >> 16) & 1u);   // RNE
  return (unsigned short)(u >> 16);
}

__device__ __forceinline__ void gload16(const unsigned short* g, unsigned short* l) {
  __builtin_amdgcn_global_load_lds(
      (const __attribute__((address_space(1))) void*)g,
      (__attribute__((address_space(3))) void*)l,
      16, 0, 0);
}

template <int OFF>
__device__ __forceinline__ bf16x8 dsr(unsigned addr) {
  iv4 r;
  asm volatile("ds_read_b128 %0, %1 offset:%2" : "=v"(r) : "v"(addr), "i"(OFF));
  return __builtin_bit_cast(bf16x8, r);
}

// ---------------- f32 -> bf16 convert (merged: x, Wq, Wk, Wv) ----------------
__global__ void cvt_all(const float* __restrict__ x, const float* __restrict__ wq,
                        const float* __restrict__ wk, const float* __restrict__ wv,
                        unsigned short* __restrict__ xb, unsigned short* __restrict__ wqb,
                        unsigned short* __restrict__ wkb, unsigned short* __restrict__ wvb) {
  const int SD = 4096 * 2048, DD = 2048 * 2048;
  int i = (blockIdx.x * 256 + threadIdx.x) * 8;
  const float* in;
  unsigned short* out;
  int off;
  if (i < SD)               { in = x;  out = xb;  off = i; }
  else if (i < SD + DD)     { in = wq; out = wqb; off = i - SD; }
  else if (i < SD + 2 * DD) { in = wk; out = wkb; off = i - SD - DD; }
  else                      { in = wv; out = wvb; off = i - SD - 2 * DD; }
  float4 a = *(const float4*)(in + off);
  float4 b = *(const float4*)(in + off + 4);
  u16x8 r;
  r[0] = f2bf(a.x); r[1] = f2bf(a.y); r[2] = f2bf(a.z); r[3] = f2bf(a.w);
  r[4] = f2bf(b.x); r[5] = f2bf(b.y); r[6] = f2bf(b.z); r[7] = f2bf(b.w);
  *(u16x8*)(out + off) = r;
}

// ---------------- 256x256 GEMM core (identical to R8) ------------------------
#define LGKM_SB()                                         \
  asm volatile("s_waitcnt lgkmcnt(0)" ::: "memory");      \
  __builtin_amdgcn_sched_barrier(0)

#define QMFMA(MB, NB, AF, BV)                                                 \
  _Pragma("unroll")                                                           \
  for (int _fm = 0; _fm < 4; ++_fm)                                           \
    _Pragma("unroll")                                                         \
    for (int _fn = 0; _fn < 2; ++_fn)                                         \
      _Pragma("unroll")                                                       \
      for (int _ks = 0; _ks < 2; ++_ks)                                       \
        acc[(MB) + _fm][(NB) + _fn] = __builtin_amdgcn_mfma_f32_16x16x32_bf16( \
            AF[_fm * 2 + _ks], BV[_fn * 2 + _ks], acc[(MB) + _fm][(NB) + _fn], \
            0, 0, 0);

#define STG_A(mhv, tau, bufv)                                                 \
  do {                                                                        \
    unsigned short* _d = lds + (bufv) * 32768 + (mhv) * 8192 + w * 512;       \
    gload16(pA + (size_t)((mhv) * 64) * KC + ((size_t)(tau) << 6), _d);       \
    gload16(pA + (size_t)(128 + (mhv) * 64) * KC + ((size_t)(tau) << 6),      \
            _d + 4096);                                                       \
  } while (0)

#define STG_B(nhv, tau, bufv)                                                 \
  do {                                                                        \
    unsigned short* _d = lds + (bufv) * 32768 + 16384 + (nhv) * 8192 + w * 512;\
    gload16(pB + (size_t)((nhv) * 32) * KC + ((size_t)(tau) << 6), _d);       \
    gload16(pB + (size_t)(128 + (nhv) * 32) * KC + ((size_t)(tau) << 6),      \
            _d + 4096);                                                       \
  } while (0)

#define VM_WAIT()                                                             \
  do {                                                                        \
    if (tail) { asm volatile("s_waitcnt vmcnt(0)" ::: "memory"); }            \
    else      { asm volatile("s_waitcnt vmcnt(8)" ::: "memory"); }            \
  } while (0)

template <int KC>
__device__ __forceinline__ void gemm_core(const unsigned short* __restrict__ Ab,
                                          const unsigned short* __restrict__ Bb,
                                          unsigned short* lds, int ktiles,
                                          f32x4 (&acc)[8][4]) {
  const int tid  = threadIdx.x;
  const int lane = tid & 63;
  const int w    = tid >> 6;          // 0..7
  const int wm   = w >> 2;            // 0..1
  const int wn   = w & 3;             // 0..3

  const int base  = w * 8 + (lane >> 3);           // 0..63
  const int gslot = (lane & 7) ^ ((lane >> 3) & 7);
  const unsigned short* pA = Ab + (size_t)base * KC + gslot * 8;
  const unsigned short* pB =
      Bb + (size_t)((base >> 5) * 64 + (base & 31)) * KC + gslot * 8;

  const unsigned lb = (unsigned)(size_t)&lds[0];
  const int rl = lane & 15, g = lane >> 4;
  const unsigned sw0 = (unsigned)(((0 + g) ^ (rl & 7)) * 16);
  const unsigned sw1 = (unsigned)(((4 + g) ^ (rl & 7)) * 16);
  const unsigned rA = lb + (unsigned)(wm * 8192 + rl * 128);
  const unsigned rB = lb + (unsigned)(wn * 4096 + rl * 128);

#pragma unroll
  for (int m = 0; m < 8; ++m)
#pragma unroll
    for (int n = 0; n < 4; ++n) acc[m][n] = f32x4{0.f, 0.f, 0.f, 0.f};

  STG_A(0, 0, 0); STG_B(0, 0, 0); STG_A(1, 0, 0); STG_B(1, 0, 0);
  if (ktiles > 1) {
    STG_A(0, 1, 1); STG_B(0, 1, 1); STG_A(1, 1, 1);
    asm volatile("s_waitcnt vmcnt(6)" ::: "memory");
  } else {
    asm volatile("s_waitcnt vmcnt(0)" ::: "memory");
  }
  __builtin_amdgcn_s_barrier();

  bf16x8 af0[8], af1[8], bv0[4], bv1[4];
  {
    const unsigned aA0 = rA + sw0, aA1 = rA + sw1;
    const unsigned aB0 = rB + sw0, aB1 = rB + sw1;
    af0[0] = dsr<0>(aA0);     af0[1] = dsr<0>(aA1);
    af0[2] = dsr<2048>(aA0);  af0[3] = dsr<2048>(aA1);
    af0[4] = dsr<4096>(aA0);  af0[5] = dsr<4096>(aA1);
    af0[6] = dsr<6144>(aA0);  af0[7] = dsr<6144>(aA1);
    bv0[0] = dsr<32768>(aB0); bv0[1] = dsr<32768>(aB1);
    bv0[2] = dsr<34816>(aB0); bv0[3] = dsr<34816>(aB1);
  }

  for (int t = 0; t < ktiles; ++t) {
    const unsigned bo  = (unsigned)(t & 1) << 16;
    const unsigned bon = (unsigned)((t + 1) & 1) << 16;
    const int buf = t & 1, nb = (t + 1) & 1;
    const bool s1 = (t + 1) < ktiles, s2 = (t + 2) < ktiles;
    const bool tail = t >= ktiles - 2;
    const unsigned aA0 = rA + bo + sw0, aA1 = rA + bo + sw1;
    const unsigned aB0 = rB + bo + sw0, aB1 = rB + bo + sw1;
    const unsigned nA0 = rA + bon + sw0, nA1 = rA + bon + sw1;
    const unsigned nB0 = rB + bon + sw0, nB1 = rB + bon + sw1;

    // ---- k0
    LGKM_SB();
    af1[0] = dsr<16384>(aA0); af1[1] = dsr<16384>(aA1);
    af1[2] = dsr<18432>(aA0); af1[3] = dsr<18432>(aA1);
    af1[4] = dsr<20480>(aA0); af1[5] = dsr<20480>(aA1);
    af1[6] = dsr<22528>(aA0); af1[7] = dsr<22528>(aA1);
    __builtin_amdgcn_sched_barrier(0);
    __builtin_amdgcn_s_setprio(1);
    QMFMA(0, 0, af0, bv0);
    __builtin_amdgcn_s_setprio(0);
    if (s1) STG_B(1, t + 1, nb);
    VM_WAIT();
    __builtin_amdgcn_s_barrier();

    // ---- k1
    LGKM_SB();
    bv1[0] = dsr<49152>(aB0); bv1[1] = dsr<49152>(aB1);
    bv1[2] = dsr<51200>(aB0); bv1[3] = dsr<51200>(aB1);
    __builtin_amdgcn_sched_barrier(0);
    __builtin_amdgcn_s_setprio(1);
    QMFMA(4, 0, af1, bv0);
    __builtin_amdgcn_s_setprio(0);
    if (s2) { STG_A(0, t + 2, buf); STG_B(0, t + 2, buf); }
    VM_WAIT();
    __builtin_amdgcn_s_barrier();

    // ---- k2
    LGKM_SB();
    if (s1) {
      bv0[0] = dsr<32768>(nB0); bv0[1] = dsr<32768>(nB1);
      bv0[2] = dsr<34816>(nB0); bv0[3] = dsr<34816>(nB1);
    }
    __builtin_amdgcn_sched_barrier(0);
    __builtin_amdgcn_s_setprio(1);
    QMFMA(0, 2, af0, bv1);
    __builtin_amdgcn_s_setprio(0);
    if (s2) STG_A(1, t + 2, buf);
    VM_WAIT();
    __builtin_amdgcn_s_barrier();

    // ---- k3
    __builtin_amdgcn_sched_barrier(0);
    if (s1) {
      af0[0] = dsr<0>(nA0);     af0[1] = dsr<0>(nA1);
      af0[2] = dsr<2048>(nA0);  af0[3] = dsr<2048>(nA1);
      af0[4] = dsr<4096>(nA0);  af0[5] = dsr<4096>(nA1);
      af0[6] = dsr<6144>(nA0);  af0[7] = dsr<6144>(nA1);
    }
    __builtin_amdgcn_sched_barrier(0);
    __builtin_amdgcn_s_setprio(1);
    QMFMA(4, 2, af1, bv1);
    __builtin_amdgcn_s_setprio(0);
    VM_WAIT();
    __builtin_amdgcn_s_barrier();
  }
}

// epilogues: C/D layout col=lane&15, row=(lane>>4)*4+reg
__device__ __forceinline__ void ep_f32(float* C, const f32x4 (&acc)[8][4],
                                       int r0, int c0, int ldc, float scale) {
  const int lane = threadIdx.x & 63, w = threadIdx.x >> 6;
  const int crow0 = r0 + (w >> 2) * 128 + ((lane >> 4) << 2);
  const int ccol0 = c0 + (w & 3) * 64 + (lane & 15);
#pragma unroll
  for (int m = 0; m < 8; ++m)
#pragma unroll
    for (int n = 0; n < 4; ++n)
#pragma unroll
      for (int j = 0; j < 4; ++j)
        C[(size_t)(crow0 + m * 16 + j) * ldc + (ccol0 + n * 16)] =
            acc[m][n][j] * scale;
}

__device__ __forceinline__ void ep_f32_at(float* C, const f32x4 (&acc)[8][4],
                                          int r0, int c0, int ldc, float scale) {
  const int lane = threadIdx.x & 63, w = threadIdx.x >> 6;
  const int crow0 = r0 + (w >> 2) * 128 + ((lane >> 4) << 2);
  const int ccol0 = c0 + (w & 3) * 64 + (lane & 15);
#pragma unroll
  for (int m = 0; m < 8; ++m)
#pragma unroll
    for (int n = 0; n < 4; ++n)
#pragma unroll
      for (int j = 0; j < 4; ++j)
        atomicAdd(&C[(size_t)(crow0 + m * 16 + j) * ldc + (ccol0 + n * 16)],
                  acc[m][n][j] * scale);
}

__device__ __forceinline__ void ep_bf16(unsigned short* C, const f32x4 (&acc)[8][4],
                                        int r0, int c0, int ldc) {
  const int lane = threadIdx.x & 63, w = threadIdx.x >> 6;
  const int crow0 = r0 + (w >> 2) * 128 + ((lane >> 4) << 2);
  const int ccol0 = c0 + (w & 3) * 64 + (lane & 15);
#pragma unroll
  for (int m = 0; m < 8; ++m)
#pragma unroll
    for (int n = 0; n < 4; ++n)
#pragma unroll
      for (int j = 0; j < 4; ++j)
        C[(size_t)(crow0 + m * 16 + j) * ldc + (ccol0 + n * 16)] =
            f2bf(acc[m][n][j]);
}

// ---------------- kernels ----------------------------------------------------
__global__ __launch_bounds__(512, 2)
void proj_qk(const unsigned short* __restrict__ xb,
             const unsigned short* __restrict__ wqb,
             const unsigned short* __restrict__ wkb,
             unsigned short* __restrict__ Q, unsigned short* __restrict__ Kb) {
  __shared__ __align__(16) unsigned short lds[65536];
  const int bid = blockIdx.x;
  const int wg = (bid & 7) * 32 + (bid >> 3);   // XCD-contiguous chunks
  const int bm = wg >> 4, bnr = wg & 15;
  const unsigned short* B = (bnr < 8) ? wqb : wkb;
  unsigned short* C = (bnr < 8) ? Q : Kb;
  const int bnl = bnr & 7;
  f32x4 acc[8][4];
  gemm_core<2048>(xb + (size_t)bm * 256 * 2048, B + (size_t)bnl * 256 * 2048,
                  lds, 32, acc);
  ep_bf16(C, acc, bm * 256, bnl * 256, 2048);
}

// vt_qkt queue: 438 jobs.
//  [0,78):    QKT triangle bm 0..11, full K (32u), write sc.
//  [78,206):  Vt tiles (128, 32u), write Vt bf16.
//  [206,438): QKT rows bm 12..15 as 4 K-chunks each (8u), atomicAdd into
//             zeroed sc rows 3072+.  Wait: rows 12..15 -> sc rows 3072..4095.
__global__ __launch_bounds__(512, 2)
void vt_qkt_q(const unsigned short* __restrict__ Qp,
              const unsigned short* __restrict__ Kp,
              const unsigned short* __restrict__ wvb,
              const unsigned short* __restrict__ xb,
              float* __restrict__ sc, unsigned short* __restrict__ Vt,
              float scale, int* __restrict__ ctr) {
  __shared__ __align__(16) unsigned short lds[65536];
  __shared__ int sid;
  f32x4 acc[8][4];
  for (;;) {
    if (threadIdx.x == 0) sid = atomicAdd(ctr, 1);
    __syncthreads();
    const int id = sid;
    if (id >= 438) return;
    if (id < 78) {
      int bm = 0;
      while ((bm + 1) * (bm + 2) / 2 <= id) ++bm;
      const int bn = id - bm * (bm + 1) / 2;
      gemm_core<2048>(Qp + (size_t)bm * 256 * 2048,
                      Kp + (size_t)bn * 256 * 2048, lds, 32, acc);
      ep_f32(sc, acc, bm * 256, bn * 256, 4096, scale);
    } else if (id < 206) {
      const int v = id - 78, bm = v >> 4, bn = v & 15;
      gemm_core<2048>(wvb + (size_t)bm * 256 * 2048,
                      xb + (size_t)bn * 256 * 2048, lds, 32, acc);
      ep_bf16(Vt, acc, bm * 256, bn * 256, 4096);
    } else {
      const int c = id - 206, tc = c >> 2, ck = c & 3;
      int bm, bn;
      if (tc < 13)      { bm = 12; bn = tc; }
      else if (tc < 27) { bm = 13; bn = tc - 13; }
      else if (tc < 42) { bm = 14; bn = tc - 27; }
      else              { bm = 15; bn = tc - 42; }
      const size_t koff = (size_t)ck * 512;   // 8 ktiles * 64
      gemm_core<2048>(Qp + (size_t)bm * 256 * 2048 + koff,
                      Kp + (size_t)bn * 256 * 2048 + koff, lds, 8, acc);
      ep_f32_at(sc, acc, bm * 256, bn * 256, 4096, scale);
    }
  }
}

// pv queue: 320 jobs, ordered bm 15 -> 0 (big pieces first).
// Job (bm,bn,p): s=(bm>>2)+1 pieces of kt=(bm+1)*4 ktiles; piece <=16u.
// bm<4 (s==1): plain write. bm>=4: atomicAdd into zeroed out rows 1024+.
__global__ __launch_bounds__(512, 2)
void pv_q(const unsigned short* __restrict__ P,
          const unsigned short* __restrict__ Vt, float* __restrict__ out,
          int* __restrict__ ctr) {
  __shared__ __align__(16) unsigned short lds[65536];
  __shared__ int sid;
  f32x4 acc[8][4];
  for (;;) {
    if (threadIdx.x == 0) sid = atomicAdd(ctr, 1);
    __syncthreads();
    const int id = sid;
    if (id >= 320) return;
    int rem = id, bm = 15, s = 4;
    for (;;) {
      s = (bm >> 2) + 1;
      const int cnt = 8 * s;
      if (rem < cnt) break;
      rem -= cnt;
      --bm;
    }
    const int bn = rem / s, p = rem % s;
    const int kt = (bm + 1) * 4;
    const int k0 = (kt * p) / s, k1 = (kt * (p + 1)) / s;
    gemm_core<4096>(P + (size_t)bm * 256 * 4096 + (size_t)k0 * 64,
                    Vt + (size_t)bn * 256 * 4096 + (size_t)k0 * 64,
                    lds, k1 - k0, acc);
    if (s == 1) ep_f32(out, acc, bm * 256, bn * 256, 2048, 1.0f);
    else        ep_f32_at(out, acc, bm * 256, bn * 256, 2048, 1.0f);
  }
}

// ---------------- causal row softmax: scores f32 -> P bf16 ------------------
__global__ void softmax_causal(const float* __restrict__ Sc,
                               unsigned short* __restrict__ P, int S) {
  const int i = blockIdx.x;
  const int tid = threadIdx.x;
  const int nvalid = i + 1;
  const int pad_end = ((i >> 8) + 1) << 8;   // 256-tile boundary
  const float* row = Sc + (size_t)i * S;

  float v[16];
  float m = -1e30f;
#pragma unroll
  for (int it = 0; it < 16; ++it) {
    const int j = tid + it * 256;
    const float x = (j < nvalid) ? row[j] : -1e30f;
    v[it] = x;
    m = fmaxf(m, x);
  }
#pragma unroll
  for (int d = 1; d < 64; d <<= 1) m = fmaxf(m, __shfl_xor(m, d));
  __shared__ float red_m[4], red_s[4];
  const int lane = tid & 63, wv = tid >> 6;
  if (lane == 0) red_m[wv] = m;
  __syncthreads();
  m = fmaxf(fmaxf(red_m[0], red_m[1]), fmaxf(red_m[2], red_m[3]));

  float s = 0.0f;
#pragma unroll
  for (int it = 0; it < 16; ++it) {
    const int j = tid + it * 256;
    const float e = (j < nvalid) ? __expf(v[it] - m) : 0.0f;
    v[it] = e;
    s += e;
  }
#pragma unroll
  for (int d = 1; d < 64; d <<= 1) s += __shfl_xor(s, d);
  if (lane == 0) red_s[wv] = s;
  __syncthreads();
  s = red_s[0] + red_s[1] + red_s[2] + red_s[3];

  const float inv = 1.0f / s;
  unsigned short* prow = P + (size_t)i * S;
#pragma unroll
  for (int it = 0; it < 16; ++it) {
    const int j = tid + it * 256;
    if (j < pad_end) prow[j] = (j < nvalid) ? f2bf(v[it] * inv) : (unsigned short)0;
  }
}

// ---------------- launch -----------------------------------------------------
extern "C" void kernel_launch(void* const* d_in, const int* in_sizes, int n_in,
                              void* d_out, int out_size, void* d_ws, size_t ws_size,
                              hipStream_t stream) {
  const float* x  = (const float*)d_in[0];
  const float* Wq = (const float*)d_in[1];
  const float* Wk = (const float*)d_in[2];
  const float* Wv = (const float*)d_in[3];
  float* out = (float*)d_out;

  const int S = 4096, D = 2048;
  char* ws = (char*)d_ws;
  const size_t MB = 1u << 20;
  // Workspace (peak 136 MiB + 16 B):
  //   sc  [  0, 64)  f32 scores            live: vt_qkt .. softmax
  //   xb  [ 64, 80)                        live: cvt .. vt_qkt
  //   wqb [ 80, 88)  wkb [88,96)           live: cvt .. proj_qk
  //   wvb [ 96,104)                        live: cvt .. vt_qkt
  //   Q   [104,120)  Kb [120,136)          live: proj_qk .. vt_qkt
  //   Vt  [ 80, 96)  (over wqb/wkb)        live: vt_qkt .. pv
  //   P   [104,136)  (over Q/Kb)           live: softmax .. pv
  //   ctr [136MB, +16B)                    queue counters (zeroed per call)
  float*          sc  = (float*)ws;
  unsigned short* xb  = (unsigned short*)(ws + 64 * MB);
  unsigned short* wqb = (unsigned short*)(ws + 80 * MB);
  unsigned short* wkb = (unsigned short*)(ws + 88 * MB);
  unsigned short* wvb = (unsigned short*)(ws + 96 * MB);
  unsigned short* Q   = (unsigned short*)(ws + 104 * MB);
  unsigned short* Kb  = (unsigned short*)(ws + 120 * MB);
  unsigned short* Vt  = (unsigned short*)(ws + 80 * MB);
  unsigned short* P   = (unsigned short*)(ws + 104 * MB);
  int*            ctr = (int*)(ws + 136 * MB);

  cvt_all<<<(S * D + 3 * D * D) / (256 * 8), 256, 0, stream>>>(
      x, Wq, Wk, Wv, xb, wqb, wkb, wvb);

  // zero queue counters + atomic target regions
  hipMemsetAsync(ctr, 0, 16, stream);
  hipMemsetAsync(sc + (size_t)3072 * 4096, 0, (size_t)1024 * 4096 * 4, stream);

  proj_qk<<<256, 512, 0, stream>>>(xb, wqb, wkb, Q, Kb);

  const float scale = 1.0f / sqrtf((float)D);
  vt_qkt_q<<<256, 512, 0, stream>>>(Q, Kb, wvb, xb, sc, Vt, scale, ctr);

  softmax_causal<<<S, 256, 0, stream>>>(sc, P, S);

  // zero out rows 1024.. (atomic targets of split pv jobs)
  hipMemsetAsync(out + (size_t)1024 * 2048, 0, (size_t)3072 * 2048 * 4, stream);

  pv_q<<<256, 512, 0, stream>>>(P, Vt, out, ctr + 1);
}

// Round 10
// 238.863 us; speedup vs baseline: 1.2564x; 1.2564x over previous
//
#include <hip/hip_runtime.h>
#include <hip/hip_bf16.h>
#include <math.h>

// S=4096, D=2048. out = causal_softmax((xWq^T)(xWk^T)^T / sqrt(D)) @ (xWv^T)
// R10 = R7 core (240µs, best verified) + pv piece-split (<=16u) through aux
// buffers in the dead sc region + add3 pass. NO bulk element atomics (R9
// lesson: 33M f32 RMW ops serialized both kernels). cvt stays merged.

typedef __attribute__((ext_vector_type(8))) short bf16x8;
typedef __attribute__((ext_vector_type(4))) float f32x4;
typedef __attribute__((ext_vector_type(8))) unsigned short u16x8;
typedef __attribute__((ext_vector_type(4))) int iv4;

__device__ __forceinline__ unsigned short f2bf(float f) {
  unsigned int u = __float_as_uint(f);
  u += 0x7FFFu + ((u >> 16) & 1u);   // RNE
  return (unsigned short)(u >> 16);
}

__device__ __forceinline__ void gload16(const unsigned short* g, unsigned short* l) {
  __builtin_amdgcn_global_load_lds(
      (const __attribute__((address_space(1))) void*)g,
      (__attribute__((address_space(3))) void*)l,
      16, 0, 0);
}

template <int OFF>
__device__ __forceinline__ bf16x8 dsr(unsigned addr) {
  iv4 r;
  asm volatile("ds_read_b128 %0, %1 offset:%2" : "=v"(r) : "v"(addr), "i"(OFF));
  return __builtin_bit_cast(bf16x8, r);
}

// ---------------- f32 -> bf16 convert (merged) -------------------------------
__global__ void cvt_all(const float* __restrict__ x, const float* __restrict__ wq,
                        const float* __restrict__ wk, const float* __restrict__ wv,
                        unsigned short* __restrict__ xb, unsigned short* __restrict__ wqb,
                        unsigned short* __restrict__ wkb, unsigned short* __restrict__ wvb) {
  const int SD = 4096 * 2048, DD = 2048 * 2048;
  int i = (blockIdx.x * 256 + threadIdx.x) * 8;
  const float* in;
  unsigned short* out;
  int off;
  if (i < SD)               { in = x;  out = xb;  off = i; }
  else if (i < SD + DD)     { in = wq; out = wqb; off = i - SD; }
  else if (i < SD + 2 * DD) { in = wk; out = wkb; off = i - SD - DD; }
  else                      { in = wv; out = wvb; off = i - SD - 2 * DD; }
  float4 a = *(const float4*)(in + off);
  float4 b = *(const float4*)(in + off + 4);
  u16x8 r;
  r[0] = f2bf(a.x); r[1] = f2bf(a.y); r[2] = f2bf(a.z); r[3] = f2bf(a.w);
  r[4] = f2bf(b.x); r[5] = f2bf(b.y); r[6] = f2bf(b.z); r[7] = f2bf(b.w);
  *(u16x8*)(out + off) = r;
}

// ---------------- 256x256 GEMM core (R7 verbatim) ----------------------------
#define LGKM_SB()                                         \
  asm volatile("s_waitcnt lgkmcnt(0)" ::: "memory");      \
  __builtin_amdgcn_sched_barrier(0)

#define QMFMA(MB, NB, AF, BV)                                                 \
  _Pragma("unroll")                                                           \
  for (int _fm = 0; _fm < 4; ++_fm)                                           \
    _Pragma("unroll")                                                         \
    for (int _fn = 0; _fn < 2; ++_fn)                                         \
      _Pragma("unroll")                                                       \
      for (int _ks = 0; _ks < 2; ++_ks)                                       \
        acc[(MB) + _fm][(NB) + _fn] = __builtin_amdgcn_mfma_f32_16x16x32_bf16( \
            AF[_fm * 2 + _ks], BV[_fn * 2 + _ks], acc[(MB) + _fm][(NB) + _fn], \
            0, 0, 0);

#define STG_A(mhv, tau, bufv)                                                 \
  do {                                                                        \
    unsigned short* _d = lds + (bufv) * 32768 + (mhv) * 8192 + w * 512;       \
    gload16(pA + (size_t)((mhv) * 64) * KC + ((size_t)(tau) << 6), _d);       \
    gload16(pA + (size_t)(128 + (mhv) * 64) * KC + ((size_t)(tau) << 6),      \
            _d + 4096);                                                       \
  } while (0)

#define STG_B(nhv, tau, bufv)                                                 \
  do {                                                                        \
    unsigned short* _d = lds + (bufv) * 32768 + 16384 + (nhv) * 8192 + w * 512;\
    gload16(pB + (size_t)((nhv) * 32) * KC + ((size_t)(tau) << 6), _d);       \
    gload16(pB + (size_t)(128 + (nhv) * 32) * KC + ((size_t)(tau) << 6),      \
            _d + 4096);                                                       \
  } while (0)

#define VM_WAIT()                                                             \
  do {                                                                        \
    if (tail) { asm volatile("s_waitcnt vmcnt(0)" ::: "memory"); }            \
    else      { asm volatile("s_waitcnt vmcnt(8)" ::: "memory"); }            \
  } while (0)

template <int KC>
__device__ __forceinline__ void gemm_core(const unsigned short* __restrict__ Ab,
                                          const unsigned short* __restrict__ Bb,
                                          unsigned short* lds, int ktiles,
                                          f32x4 (&acc)[8][4]) {
  const int tid  = threadIdx.x;
  const int lane = tid & 63;
  const int w    = tid >> 6;          // 0..7
  const int wm   = w >> 2;            // 0..1
  const int wn   = w & 3;             // 0..3

  const int base  = w * 8 + (lane >> 3);           // 0..63
  const int gslot = (lane & 7) ^ ((lane >> 3) & 7);
  const unsigned short* pA = Ab + (size_t)base * KC + gslot * 8;
  const unsigned short* pB =
      Bb + (size_t)((base >> 5) * 64 + (base & 31)) * KC + gslot * 8;

  const unsigned lb = (unsigned)(size_t)&lds[0];
  const int rl = lane & 15, g = lane >> 4;
  const unsigned sw0 = (unsigned)(((0 + g) ^ (rl & 7)) * 16);
  const unsigned sw1 = (unsigned)(((4 + g) ^ (rl & 7)) * 16);
  const unsigned rA = lb + (unsigned)(wm * 8192 + rl * 128);
  const unsigned rB = lb + (unsigned)(wn * 4096 + rl * 128);

#pragma unroll
  for (int m = 0; m < 8; ++m)
#pragma unroll
    for (int n = 0; n < 4; ++n) acc[m][n] = f32x4{0.f, 0.f, 0.f, 0.f};

  STG_A(0, 0, 0); STG_B(0, 0, 0); STG_A(1, 0, 0); STG_B(1, 0, 0);
  if (ktiles > 1) {
    STG_A(0, 1, 1); STG_B(0, 1, 1); STG_A(1, 1, 1);
    asm volatile("s_waitcnt vmcnt(6)" ::: "memory");
  } else {
    asm volatile("s_waitcnt vmcnt(0)" ::: "memory");
  }
  __builtin_amdgcn_s_barrier();

  bf16x8 af0[8], af1[8], bv0[4], bv1[4];
  {
    const unsigned aA0 = rA + sw0, aA1 = rA + sw1;
    const unsigned aB0 = rB + sw0, aB1 = rB + sw1;
    af0[0] = dsr<0>(aA0);     af0[1] = dsr<0>(aA1);
    af0[2] = dsr<2048>(aA0);  af0[3] = dsr<2048>(aA1);
    af0[4] = dsr<4096>(aA0);  af0[5] = dsr<4096>(aA1);
    af0[6] = dsr<6144>(aA0);  af0[7] = dsr<6144>(aA1);
    bv0[0] = dsr<32768>(aB0); bv0[1] = dsr<32768>(aB1);
    bv0[2] = dsr<34816>(aB0); bv0[3] = dsr<34816>(aB1);
  }

  for (int t = 0; t < ktiles; ++t) {
    const unsigned bo  = (unsigned)(t & 1) << 16;
    const unsigned bon = (unsigned)((t + 1) & 1) << 16;
    const int buf = t & 1, nb = (t + 1) & 1;
    const bool s1 = (t + 1) < ktiles, s2 = (t + 2) < ktiles;
    const bool tail = t >= ktiles - 2;
    const unsigned aA0 = rA + bo + sw0, aA1 = rA + bo + sw1;
    const unsigned aB0 = rB + bo + sw0, aB1 = rB + bo + sw1;
    const unsigned nA0 = rA + bon + sw0, nA1 = rA + bon + sw1;
    const unsigned nB0 = rB + bon + sw0, nB1 = rB + bon + sw1;

    // ---- k0: MFMA(00) | issue af1(t) | stage B-n1(t+1)
    LGKM_SB();
    __builtin_amdgcn_s_setprio(1);
    QMFMA(0, 0, af0, bv0);
    __builtin_amdgcn_s_setprio(0);
    af1[0] = dsr<16384>(aA0); af1[1] = dsr<16384>(aA1);
    af1[2] = dsr<18432>(aA0); af1[3] = dsr<18432>(aA1);
    af1[4] = dsr<20480>(aA0); af1[5] = dsr<20480>(aA1);
    af1[6] = dsr<22528>(aA0); af1[7] = dsr<22528>(aA1);
    if (s1) STG_B(1, t + 1, nb);
    VM_WAIT();
    __builtin_amdgcn_s_barrier();

    // ---- k1: MFMA(10) | issue bv1(t) | stage A-h0,B-n0(t+2)
    LGKM_SB();
    __builtin_amdgcn_s_setprio(1);
    QMFMA(4, 0, af1, bv0);
    __builtin_amdgcn_s_setprio(0);
    bv1[0] = dsr<49152>(aB0); bv1[1] = dsr<49152>(aB1);
    bv1[2] = dsr<51200>(aB0); bv1[3] = dsr<51200>(aB1);
    if (s2) { STG_A(0, t + 2, buf); STG_B(0, t + 2, buf); }
    VM_WAIT();
    __builtin_amdgcn_s_barrier();

    // ---- k2: MFMA(01) | issue af0',bv0'(t+1) | stage A-h1(t+2)
    LGKM_SB();
    __builtin_amdgcn_s_setprio(1);
    QMFMA(0, 2, af0, bv1);
    __builtin_amdgcn_s_setprio(0);
    if (s1) {
      af0[0] = dsr<0>(nA0);     af0[1] = dsr<0>(nA1);
      af0[2] = dsr<2048>(nA0);  af0[3] = dsr<2048>(nA1);
      af0[4] = dsr<4096>(nA0);  af0[5] = dsr<4096>(nA1);
      af0[6] = dsr<6144>(nA0);  af0[7] = dsr<6144>(nA1);
      bv0[0] = dsr<32768>(nB0); bv0[1] = dsr<32768>(nB1);
      bv0[2] = dsr<34816>(nB0); bv0[3] = dsr<34816>(nB1);
    }
    if (s2) STG_A(1, t + 2, buf);
    VM_WAIT();
    __builtin_amdgcn_s_barrier();

    // ---- k3: MFMA(11) | no reads
    __builtin_amdgcn_sched_barrier(0);
    __builtin_amdgcn_s_setprio(1);
    QMFMA(4, 2, af1, bv1);
    __builtin_amdgcn_s_setprio(0);
    VM_WAIT();
    __builtin_amdgcn_s_barrier();
  }
}

// epilogues: C/D layout col=lane&15, row=(lane>>4)*4+reg
__device__ __forceinline__ void ep_f32(float* C, const f32x4 (&acc)[8][4],
                                       int r0, int c0, int ldc, float scale) {
  const int lane = threadIdx.x & 63, w = threadIdx.x >> 6;
  const int crow0 = r0 + (w >> 2) * 128 + ((lane >> 4) << 2);
  const int ccol0 = c0 + (w & 3) * 64 + (lane & 15);
#pragma unroll
  for (int m = 0; m < 8; ++m)
#pragma unroll
    for (int n = 0; n < 4; ++n)
#pragma unroll
      for (int j = 0; j < 4; ++j)
        C[(size_t)(crow0 + m * 16 + j) * ldc + (ccol0 + n * 16)] =
            acc[m][n][j] * scale;
}

__device__ __forceinline__ void ep_f32_at(float* C, const f32x4 (&acc)[8][4],
                                          int r0, int c0, int ldc, float scale) {
  const int lane = threadIdx.x & 63, w = threadIdx.x >> 6;
  const int crow0 = r0 + (w >> 2) * 128 + ((lane >> 4) << 2);
  const int ccol0 = c0 + (w & 3) * 64 + (lane & 15);
#pragma unroll
  for (int m = 0; m < 8; ++m)
#pragma unroll
    for (int n = 0; n < 4; ++n)
#pragma unroll
      for (int j = 0; j < 4; ++j)
        atomicAdd(&C[(size_t)(crow0 + m * 16 + j) * ldc + (ccol0 + n * 16)],
                  acc[m][n][j] * scale);
}

__device__ __forceinline__ void ep_bf16(unsigned short* C, const f32x4 (&acc)[8][4],
                                        int r0, int c0, int ldc) {
  const int lane = threadIdx.x & 63, w = threadIdx.x >> 6;
  const int crow0 = r0 + (w >> 2) * 128 + ((lane >> 4) << 2);
  const int ccol0 = c0 + (w & 3) * 64 + (lane & 15);
#pragma unroll
  for (int m = 0; m < 8; ++m)
#pragma unroll
    for (int n = 0; n < 4; ++n)
#pragma unroll
      for (int j = 0; j < 4; ++j)
        C[(size_t)(crow0 + m * 16 + j) * ldc + (ccol0 + n * 16)] =
            f2bf(acc[m][n][j]);
}

// ---------------- kernels ----------------------------------------------------
__global__ __launch_bounds__(512, 2)
void proj_qk(const unsigned short* __restrict__ xb,
             const unsigned short* __restrict__ wqb,
             const unsigned short* __restrict__ wkb,
             unsigned short* __restrict__ Q, unsigned short* __restrict__ Kb) {
  __shared__ __align__(16) unsigned short lds[65536];
  const int bid = blockIdx.x;
  const int wg = (bid & 7) * 32 + (bid >> 3);   // XCD-contiguous chunks
  const int bm = wg >> 4, bnr = wg & 15;
  const unsigned short* B = (bnr < 8) ? wqb : wkb;
  unsigned short* C = (bnr < 8) ? Q : Kb;
  const int bnl = bnr & 7;
  f32x4 acc[8][4];
  gemm_core<2048>(xb + (size_t)bm * 256 * 2048, B + (size_t)bnl * 256 * 2048,
                  lds, 32, acc);
  ep_bf16(C, acc, bm * 256, bnl * 256, 2048);
}

// R7 static layout: [0,64): bm=15 QKT K-chunks (8u, atomicAdd, 16MB total);
// [64,184): full QKT bm 0..14; [184,312): Vt tiles.
__global__ __launch_bounds__(512, 2)
void vt_qkt(const unsigned short* __restrict__ Qp,
            const unsigned short* __restrict__ Kp,
            const unsigned short* __restrict__ wvb,
            const unsigned short* __restrict__ xb,
            float* __restrict__ sc, unsigned short* __restrict__ Vt,
            float scale) {
  __shared__ __align__(16) unsigned short lds[65536];
  const int id = blockIdx.x;
  f32x4 acc[8][4];
  if (id < 64) {
    const int p = id >> 2, c = id & 3;
    const size_t koff = (size_t)c * 8 * 64;
    gemm_core<2048>(Qp + (size_t)15 * 256 * 2048 + koff,
                    Kp + (size_t)p * 256 * 2048 + koff, lds, 8, acc);
    ep_f32_at(sc, acc, 3840, p * 256, 4096, scale);
  } else if (id < 184) {
    const int q = id - 64;
    int bm = 0;
    while ((bm + 1) * (bm + 2) / 2 <= q) ++bm;
    const int bn = q - bm * (bm + 1) / 2;
    gemm_core<2048>(Qp + (size_t)bm * 256 * 2048,
                    Kp + (size_t)bn * 256 * 2048, lds, 32, acc);
    ep_f32(sc, acc, bm * 256, bn * 256, 4096, scale);
  } else {
    const int v = id - 184, bm = v >> 4, bn = v & 15;
    gemm_core<2048>(wvb + (size_t)bm * 256 * 2048,
                    xb + (size_t)bn * 256 * 2048, lds, 32, acc);
    ep_bf16(Vt, acc, bm * 256, bn * 256, 4096);
  }
}

// pv queue: 320 jobs, bm descending (LPT). (bm,bn) split into s=(bm>>2)+1
// K-pieces (all <=16u). Piece 0 -> out; pieces 1..3 -> aux1/2/3 (plain
// writes into dead-sc space); add3 combines. Queue atomic = 1 op/job.
__global__ __launch_bounds__(512, 2)
void pv_q(const unsigned short* __restrict__ P,
          const unsigned short* __restrict__ Vt, float* __restrict__ out,
          float* __restrict__ aux1, float* __restrict__ aux2,
          float* __restrict__ aux3, int* __restrict__ ctr) {
  __shared__ __align__(16) unsigned short lds[65536];
  __shared__ int sid;
  f32x4 acc[8][4];
  for (;;) {
    if (threadIdx.x == 0) sid = atomicAdd(ctr, 1);
    __syncthreads();
    const int id = sid;
    if (id >= 320) return;
    int rem = id, bm = 15, s = 4;
    for (;;) {
      s = (bm >> 2) + 1;
      const int cnt = 8 * s;
      if (rem < cnt) break;
      rem -= cnt;
      --bm;
    }
    const int bn = rem / s, p = rem % s;
    const int kt = (bm + 1) * 4;
    const int k0 = (kt * p) / s, k1 = (kt * (p + 1)) / s;
    gemm_core<4096>(P + (size_t)bm * 256 * 4096 + (size_t)k0 * 64,
                    Vt + (size_t)bn * 256 * 4096 + (size_t)k0 * 64,
                    lds, k1 - k0, acc);
    if (p == 0)      ep_f32(out,  acc, bm * 256,        bn * 256, 2048, 1.0f);
    else if (p == 1) ep_f32(aux1, acc, bm * 256 - 1024, bn * 256, 2048, 1.0f);
    else if (p == 2) ep_f32(aux2, acc, bm * 256 - 2048, bn * 256, 2048, 1.0f);
    else             ep_f32(aux3, acc, bm * 256 - 3072, bn * 256, 2048, 1.0f);
  }
}

// out rows 1024.. += aux1 (+aux2 rows>=2048) (+aux3 rows>=3072)
__global__ void add3(float* __restrict__ out, const float* __restrict__ aux1,
                     const float* __restrict__ aux2, const float* __restrict__ aux3) {
  const size_t i = ((size_t)blockIdx.x * 256 + threadIdx.x) * 8;  // 0..3072*2048
  const int row = 1024 + (int)(i >> 11);
  float* o = out + (size_t)1024 * 2048 + i;
  f32x4 a0 = *(const f32x4*)o;
  f32x4 a1 = *(const f32x4*)(o + 4);
  a0 += *(const f32x4*)(aux1 + i);
  a1 += *(const f32x4*)(aux1 + i + 4);
  if (row >= 2048) {
    const size_t j = i - (size_t)1024 * 2048;
    a0 += *(const f32x4*)(aux2 + j);
    a1 += *(const f32x4*)(aux2 + j + 4);
  }
  if (row >= 3072) {
    const size_t j = i - (size_t)2048 * 2048;
    a0 += *(const f32x4*)(aux3 + j);
    a1 += *(const f32x4*)(aux3 + j + 4);
  }
  *(f32x4*)o = a0;
  *(f32x4*)(o + 4) = a1;
}

// ---------------- causal row softmax: scores f32 -> P bf16 ------------------
__global__ void softmax_causal(const float* __restrict__ Sc,
                               unsigned short* __restrict__ P, int S) {
  const int i = blockIdx.x;
  const int tid = threadIdx.x;
  const int nvalid = i + 1;
  const int pad_end = ((i >> 8) + 1) << 8;   // 256-tile boundary
  const float* row = Sc + (size_t)i * S;

  float v[16];
  float m = -1e30f;
#pragma unroll
  for (int it = 0; it < 16; ++it) {
    const int j = tid + it * 256;
    const float x = (j < nvalid) ? row[j] : -1e30f;
    v[it] = x;
    m = fmaxf(m, x);
  }
#pragma unroll
  for (int d = 1; d < 64; d <<= 1) m = fmaxf(m, __shfl_xor(m, d));
  __shared__ float red_m[4], red_s[4];
  const int lane = tid & 63, wv = tid >> 6;
  if (lane == 0) red_m[wv] = m;
  __syncthreads();
  m = fmaxf(fmaxf(red_m[0], red_m[1]), fmaxf(red_m[2], red_m[3]));

  float s = 0.0f;
#pragma unroll
  for (int it = 0; it < 16; ++it) {
    const int j = tid + it * 256;
    const float e = (j < nvalid) ? __expf(v[it] - m) : 0.0f;
    v[it] = e;
    s += e;
  }
#pragma unroll
  for (int d = 1; d < 64; d <<= 1) s += __shfl_xor(s, d);
  if (lane == 0) red_s[wv] = s;
  __syncthreads();
  s = red_s[0] + red_s[1] + red_s[2] + red_s[3];

  const float inv = 1.0f / s;
  unsigned short* prow = P + (size_t)i * S;
#pragma unroll
  for (int it = 0; it < 16; ++it) {
    const int j = tid + it * 256;
    if (j < pad_end) prow[j] = (j < nvalid) ? f2bf(v[it] * inv) : (unsigned short)0;
  }
}

// ---------------- launch -----------------------------------------------------
extern "C" void kernel_launch(void* const* d_in, const int* in_sizes, int n_in,
                              void* d_out, int out_size, void* d_ws, size_t ws_size,
                              hipStream_t stream) {
  const float* x  = (const float*)d_in[0];
  const float* Wq = (const float*)d_in[1];
  const float* Wk = (const float*)d_in[2];
  const float* Wv = (const float*)d_in[3];
  float* out = (float*)d_out;

  const int S = 4096, D = 2048;
  char* ws = (char*)d_ws;
  const size_t MB = 1u << 20;
  // Workspace (peak 136 MiB + 16 B):
  //   sc   [  0, 64)  f32 scores           live: vt_qkt .. softmax
  //   aux1 [  0, 24)  aux2 [24,40) aux3 [40,48)  (over dead sc)  pv .. add3
  //   xb   [ 64, 80)                       live: cvt .. vt_qkt
  //   wqb  [ 80, 88)  wkb [88,96)          live: cvt .. proj_qk
  //   wvb  [ 96,104)                       live: cvt .. vt_qkt
  //   Q    [104,120)  Kb [120,136)         live: proj_qk .. vt_qkt
  //   Vt   [ 80, 96)  (over wqb/wkb)       live: vt_qkt .. pv
  //   P    [104,136)  (over Q/Kb)          live: softmax .. pv
  //   ctr  [136MB,+16B)
  float*          sc   = (float*)ws;
  float*          aux1 = (float*)ws;
  float*          aux2 = (float*)(ws + 24 * MB);
  float*          aux3 = (float*)(ws + 40 * MB);
  unsigned short* xb   = (unsigned short*)(ws + 64 * MB);
  unsigned short* wqb  = (unsigned short*)(ws + 80 * MB);
  unsigned short* wkb  = (unsigned short*)(ws + 88 * MB);
  unsigned short* wvb  = (unsigned short*)(ws + 96 * MB);
  unsigned short* Q    = (unsigned short*)(ws + 104 * MB);
  unsigned short* Kb   = (unsigned short*)(ws + 120 * MB);
  unsigned short* Vt   = (unsigned short*)(ws + 80 * MB);
  unsigned short* P    = (unsigned short*)(ws + 104 * MB);
  int*            ctr  = (int*)(ws + 136 * MB);

  cvt_all<<<(S * D + 3 * D * D) / (256 * 8), 256, 0, stream>>>(
      x, Wq, Wk, Wv, xb, wqb, wkb, wvb);

  hipMemsetAsync(ctr, 0, 16, stream);
  // zero sc rows 3840..4095 (atomic targets of the 64 QKT chunk jobs)
  hipMemsetAsync(sc + (size_t)3840 * 4096, 0, (size_t)256 * 4096 * 4, stream);

  proj_qk<<<256, 512, 0, stream>>>(xb, wqb, wkb, Q, Kb);

  const float scale = 1.0f / sqrtf((float)D);
  vt_qkt<<<312, 512, 0, stream>>>(Q, Kb, wvb, xb, sc, Vt, scale);

  softmax_causal<<<S, 256, 0, stream>>>(sc, P, S);

  pv_q<<<256, 512, 0, stream>>>(P, Vt, out, aux1, aux2, aux3, ctr);
  add3<<<3072, 256, 0, stream>>>(out, aux1, aux2, aux3);
}

// Round 11
// 237.577 us; speedup vs baseline: 1.2632x; 1.0054x over previous
//
#include <hip/hip_runtime.h>
#include <hip/hip_bf16.h>
#include <math.h>

// S=4096, D=2048. out = causal_softmax((xWq^T)(xWk^T)^T / sqrt(D)) @ (xWv^T)
// R11 = R10 grids/jobs + merged 2-phase gemm_core (2 barriers + 2 counted
// vmcnt waits per K-tile, was 4+4) + pv aux in bf16 (add3 traffic -40%).

typedef __attribute__((ext_vector_type(8))) short bf16x8;
typedef __attribute__((ext_vector_type(4))) float f32x4;
typedef __attribute__((ext_vector_type(8))) unsigned short u16x8;
typedef __attribute__((ext_vector_type(4))) int iv4;

__device__ __forceinline__ unsigned short f2bf(float f) {
  unsigned int u = __float_as_uint(f);
  u += 0x7FFFu + ((u >> 16) & 1u);   // RNE
  return (unsigned short)(u >> 16);
}
__device__ __forceinline__ float bf2f(unsigned short u) {
  return __uint_as_float((unsigned int)u << 16);
}

__device__ __forceinline__ void gload16(const unsigned short* g, unsigned short* l) {
  __builtin_amdgcn_global_load_lds(
      (const __attribute__((address_space(1))) void*)g,
      (__attribute__((address_space(3))) void*)l,
      16, 0, 0);
}

template <int OFF>
__device__ __forceinline__ bf16x8 dsr(unsigned addr) {
  iv4 r;
  asm volatile("ds_read_b128 %0, %1 offset:%2" : "=v"(r) : "v"(addr), "i"(OFF));
  return __builtin_bit_cast(bf16x8, r);
}

// ---------------- f32 -> bf16 convert (merged) -------------------------------
__global__ void cvt_all(const float* __restrict__ x, const float* __restrict__ wq,
                        const float* __restrict__ wk, const float* __restrict__ wv,
                        unsigned short* __restrict__ xb, unsigned short* __restrict__ wqb,
                        unsigned short* __restrict__ wkb, unsigned short* __restrict__ wvb) {
  const int SD = 4096 * 2048, DD = 2048 * 2048;
  int i = (blockIdx.x * 256 + threadIdx.x) * 8;
  const float* in;
  unsigned short* out;
  int off;
  if (i < SD)               { in = x;  out = xb;  off = i; }
  else if (i < SD + DD)     { in = wq; out = wqb; off = i - SD; }
  else if (i < SD + 2 * DD) { in = wk; out = wkb; off = i - SD - DD; }
  else                      { in = wv; out = wvb; off = i - SD - 2 * DD; }
  float4 a = *(const float4*)(in + off);
  float4 b = *(const float4*)(in + off + 4);
  u16x8 r;
  r[0] = f2bf(a.x); r[1] = f2bf(a.y); r[2] = f2bf(a.z); r[3] = f2bf(a.w);
  r[4] = f2bf(b.x); r[5] = f2bf(b.y); r[6] = f2bf(b.z); r[7] = f2bf(b.w);
  *(u16x8*)(out + off) = r;
}

// ---------------- 256x256 GEMM core (merged 2-phase) -------------------------
// Layout identical to R5..R10 (verified). Per K-tile:
//  phaseA: lgkm[af0,bv0] | issue af1,bv1 | MFMA(00) | lgkm[af1,bv1] | MFMA(10)
//          | stage B-n1(t+1), A-h0(t+2), B-n0(t+2) | vmcnt(8) | barrier
//  phaseB: MFMA(01) | issue af0',bv0'(t+1) | MFMA(11) | stage A-h1(t+2)
//          | vmcnt(6) | barrier
// FIFO: B-n0(t+1) 8-newer at A-end -> vmcnt(8); B-n1(t+1)/A-h1(t+1) 6/8-newer
// at B-end -> vmcnt(6). LDS WAR: staged regions' reads drained >=1 barrier
// earlier. Reg WAR: af0'/bv0' issued after MFMA(01) (R7-precedented).
#define LGKM_SB()                                         \
  asm volatile("s_waitcnt lgkmcnt(0)" ::: "memory");      \
  __builtin_amdgcn_sched_barrier(0)

#define QMFMA(MB, NB, AF, BV)                                                 \
  _Pragma("unroll")                                                           \
  for (int _fm = 0; _fm < 4; ++_fm)                                           \
    _Pragma("unroll")                                                         \
    for (int _fn = 0; _fn < 2; ++_fn)                                         \
      _Pragma("unroll")                                                       \
      for (int _ks = 0; _ks < 2; ++_ks)                                       \
        acc[(MB) + _fm][(NB) + _fn] = __builtin_amdgcn_mfma_f32_16x16x32_bf16( \
            AF[_fm * 2 + _ks], BV[_fn * 2 + _ks], acc[(MB) + _fm][(NB) + _fn], \
            0, 0, 0);

#define STG_A(mhv, tau, bufv)                                                 \
  do {                                                                        \
    unsigned short* _d = lds + (bufv) * 32768 + (mhv) * 8192 + w * 512;       \
    gload16(pA + (size_t)((mhv) * 64) * KC + ((size_t)(tau) << 6), _d);       \
    gload16(pA + (size_t)(128 + (mhv) * 64) * KC + ((size_t)(tau) << 6),      \
            _d + 4096);                                                       \
  } while (0)

#define STG_B(nhv, tau, bufv)                                                 \
  do {                                                                        \
    unsigned short* _d = lds + (bufv) * 32768 + 16384 + (nhv) * 8192 + w * 512;\
    gload16(pB + (size_t)((nhv) * 32) * KC + ((size_t)(tau) << 6), _d);       \
    gload16(pB + (size_t)(128 + (nhv) * 32) * KC + ((size_t)(tau) << 6),      \
            _d + 4096);                                                       \
  } while (0)

template <int KC>
__device__ __forceinline__ void gemm_core(const unsigned short* __restrict__ Ab,
                                          const unsigned short* __restrict__ Bb,
                                          unsigned short* lds, int ktiles,
                                          f32x4 (&acc)[8][4]) {
  const int tid  = threadIdx.x;
  const int lane = tid & 63;
  const int w    = tid >> 6;          // 0..7
  const int wm   = w >> 2;            // 0..1
  const int wn   = w & 3;             // 0..3

  const int base  = w * 8 + (lane >> 3);           // 0..63
  const int gslot = (lane & 7) ^ ((lane >> 3) & 7);
  const unsigned short* pA = Ab + (size_t)base * KC + gslot * 8;
  const unsigned short* pB =
      Bb + (size_t)((base >> 5) * 64 + (base & 31)) * KC + gslot * 8;

  const unsigned lb = (unsigned)(size_t)&lds[0];
  const int rl = lane & 15, g = lane >> 4;
  const unsigned sw0 = (unsigned)(((0 + g) ^ (rl & 7)) * 16);
  const unsigned sw1 = (unsigned)(((4 + g) ^ (rl & 7)) * 16);
  const unsigned rA = lb + (unsigned)(wm * 8192 + rl * 128);
  const unsigned rB = lb + (unsigned)(wn * 4096 + rl * 128);

#pragma unroll
  for (int m = 0; m < 8; ++m)
#pragma unroll
    for (int n = 0; n < 4; ++n) acc[m][n] = f32x4{0.f, 0.f, 0.f, 0.f};

  STG_A(0, 0, 0); STG_B(0, 0, 0); STG_A(1, 0, 0); STG_B(1, 0, 0);
  if (ktiles > 1) {
    STG_A(0, 1, 1); STG_B(0, 1, 1); STG_A(1, 1, 1);
    asm volatile("s_waitcnt vmcnt(6)" ::: "memory");
  } else {
    asm volatile("s_waitcnt vmcnt(0)" ::: "memory");
  }
  __builtin_amdgcn_s_barrier();

  bf16x8 af0[8], af1[8], bv0[4], bv1[4];
  {  // prime t0's (mh0,nh0) operands
    const unsigned aA0 = rA + sw0, aA1 = rA + sw1;
    const unsigned aB0 = rB + sw0, aB1 = rB + sw1;
    af0[0] = dsr<0>(aA0);     af0[1] = dsr<0>(aA1);
    af0[2] = dsr<2048>(aA0);  af0[3] = dsr<2048>(aA1);
    af0[4] = dsr<4096>(aA0);  af0[5] = dsr<4096>(aA1);
    af0[6] = dsr<6144>(aA0);  af0[7] = dsr<6144>(aA1);
    bv0[0] = dsr<32768>(aB0); bv0[1] = dsr<32768>(aB1);
    bv0[2] = dsr<34816>(aB0); bv0[3] = dsr<34816>(aB1);
  }

  for (int t = 0; t < ktiles; ++t) {
    const unsigned bo  = (unsigned)(t & 1) << 16;
    const unsigned bon = (unsigned)((t + 1) & 1) << 16;
    const int buf = t & 1, nb = (t + 1) & 1;
    const bool s1 = (t + 1) < ktiles, s2 = (t + 2) < ktiles;
    const bool tail = t >= ktiles - 2;
    const unsigned aA0 = rA + bo + sw0, aA1 = rA + bo + sw1;
    const unsigned aB0 = rB + bo + sw0, aB1 = rB + bo + sw1;
    const unsigned nA0 = rA + bon + sw0, nA1 = rA + bon + sw1;
    const unsigned nB0 = rB + bon + sw0, nB1 = rB + bon + sw1;

    // ================= phase A =================
    LGKM_SB();                                // af0,bv0 of tile t landed
    af1[0] = dsr<16384>(aA0); af1[1] = dsr<16384>(aA1);
    af1[2] = dsr<18432>(aA0); af1[3] = dsr<18432>(aA1);
    af1[4] = dsr<20480>(aA0); af1[5] = dsr<20480>(aA1);
    af1[6] = dsr<22528>(aA0); af1[7] = dsr<22528>(aA1);
    bv1[0] = dsr<49152>(aB0); bv1[1] = dsr<49152>(aB1);
    bv1[2] = dsr<51200>(aB0); bv1[3] = dsr<51200>(aB1);
    __builtin_amdgcn_sched_barrier(0);
    __builtin_amdgcn_s_setprio(1);
    QMFMA(0, 0, af0, bv0);
    __builtin_amdgcn_s_setprio(0);
    LGKM_SB();                                // af1,bv1 landed
    __builtin_amdgcn_s_setprio(1);
    QMFMA(4, 0, af1, bv0);
    __builtin_amdgcn_s_setprio(0);
    if (s1) STG_B(1, t + 1, nb);
    if (s2) { STG_A(0, t + 2, buf); STG_B(0, t + 2, buf); }
    if (tail) { asm volatile("s_waitcnt vmcnt(0)" ::: "memory"); }
    else      { asm volatile("s_waitcnt vmcnt(8)" ::: "memory"); }
    __builtin_amdgcn_s_barrier();

    // ================= phase B =================
    __builtin_amdgcn_sched_barrier(0);
    __builtin_amdgcn_s_setprio(1);
    QMFMA(0, 2, af0, bv1);
    __builtin_amdgcn_s_setprio(0);
    if (s1) {                                 // issue t+1 (after last af0/bv0 use)
      af0[0] = dsr<0>(nA0);     af0[1] = dsr<0>(nA1);
      af0[2] = dsr<2048>(nA0);  af0[3] = dsr<2048>(nA1);
      af0[4] = dsr<4096>(nA0);  af0[5] = dsr<4096>(nA1);
      af0[6] = dsr<6144>(nA0);  af0[7] = dsr<6144>(nA1);
      bv0[0] = dsr<32768>(nB0); bv0[1] = dsr<32768>(nB1);
      bv0[2] = dsr<34816>(nB0); bv0[3] = dsr<34816>(nB1);
    }
    __builtin_amdgcn_sched_barrier(0);
    __builtin_amdgcn_s_setprio(1);
    QMFMA(4, 2, af1, bv1);
    __builtin_amdgcn_s_setprio(0);
    if (s2) STG_A(1, t + 2, buf);
    if (tail) { asm volatile("s_waitcnt vmcnt(0)" ::: "memory"); }
    else      { asm volatile("s_waitcnt vmcnt(6)" ::: "memory"); }
    __builtin_amdgcn_s_barrier();
  }
}

// epilogues: C/D layout col=lane&15, row=(lane>>4)*4+reg
__device__ __forceinline__ void ep_f32(float* C, const f32x4 (&acc)[8][4],
                                       int r0, int c0, int ldc, float scale) {
  const int lane = threadIdx.x & 63, w = threadIdx.x >> 6;
  const int crow0 = r0 + (w >> 2) * 128 + ((lane >> 4) << 2);
  const int ccol0 = c0 + (w & 3) * 64 + (lane & 15);
#pragma unroll
  for (int m = 0; m < 8; ++m)
#pragma unroll
    for (int n = 0; n < 4; ++n)
#pragma unroll
      for (int j = 0; j < 4; ++j)
        C[(size_t)(crow0 + m * 16 + j) * ldc + (ccol0 + n * 16)] =
            acc[m][n][j] * scale;
}

__device__ __forceinline__ void ep_f32_at(float* C, const f32x4 (&acc)[8][4],
                                          int r0, int c0, int ldc, float scale) {
  const int lane = threadIdx.x & 63, w = threadIdx.x >> 6;
  const int crow0 = r0 + (w >> 2) * 128 + ((lane >> 4) << 2);
  const int ccol0 = c0 + (w & 3) * 64 + (lane & 15);
#pragma unroll
  for (int m = 0; m < 8; ++m)
#pragma unroll
    for (int n = 0; n < 4; ++n)
#pragma unroll
      for (int j = 0; j < 4; ++j)
        atomicAdd(&C[(size_t)(crow0 + m * 16 + j) * ldc + (ccol0 + n * 16)],
                  acc[m][n][j] * scale);
}

__device__ __forceinline__ void ep_bf16(unsigned short* C, const f32x4 (&acc)[8][4],
                                        int r0, int c0, int ldc) {
  const int lane = threadIdx.x & 63, w = threadIdx.x >> 6;
  const int crow0 = r0 + (w >> 2) * 128 + ((lane >> 4) << 2);
  const int ccol0 = c0 + (w & 3) * 64 + (lane & 15);
#pragma unroll
  for (int m = 0; m < 8; ++m)
#pragma unroll
    for (int n = 0; n < 4; ++n)
#pragma unroll
      for (int j = 0; j < 4; ++j)
        C[(size_t)(crow0 + m * 16 + j) * ldc + (ccol0 + n * 16)] =
            f2bf(acc[m][n][j]);
}

// ---------------- kernels ----------------------------------------------------
__global__ __launch_bounds__(512, 2)
void proj_qk(const unsigned short* __restrict__ xb,
             const unsigned short* __restrict__ wqb,
             const unsigned short* __restrict__ wkb,
             unsigned short* __restrict__ Q, unsigned short* __restrict__ Kb) {
  __shared__ __align__(16) unsigned short lds[65536];
  const int bid = blockIdx.x;
  const int wg = (bid & 7) * 32 + (bid >> 3);   // XCD-contiguous chunks
  const int bm = wg >> 4, bnr = wg & 15;
  const unsigned short* B = (bnr < 8) ? wqb : wkb;
  unsigned short* C = (bnr < 8) ? Q : Kb;
  const int bnl = bnr & 7;
  f32x4 acc[8][4];
  gemm_core<2048>(xb + (size_t)bm * 256 * 2048, B + (size_t)bnl * 256 * 2048,
                  lds, 32, acc);
  ep_bf16(C, acc, bm * 256, bnl * 256, 2048);
}

// [0,64): bm=15 QKT K-chunks (8u, atomicAdd into zeroed sc rows 3840+);
// [64,184): full QKT bm 0..14; [184,312): Vt tiles.
__global__ __launch_bounds__(512, 2)
void vt_qkt(const unsigned short* __restrict__ Qp,
            const unsigned short* __restrict__ Kp,
            const unsigned short* __restrict__ wvb,
            const unsigned short* __restrict__ xb,
            float* __restrict__ sc, unsigned short* __restrict__ Vt,
            float scale) {
  __shared__ __align__(16) unsigned short lds[65536];
  const int id = blockIdx.x;
  f32x4 acc[8][4];
  if (id < 64) {
    const int p = id >> 2, c = id & 3;
    const size_t koff = (size_t)c * 8 * 64;
    gemm_core<2048>(Qp + (size_t)15 * 256 * 2048 + koff,
                    Kp + (size_t)p * 256 * 2048 + koff, lds, 8, acc);
    ep_f32_at(sc, acc, 3840, p * 256, 4096, scale);
  } else if (id < 184) {
    const int q = id - 64;
    int bm = 0;
    while ((bm + 1) * (bm + 2) / 2 <= q) ++bm;
    const int bn = q - bm * (bm + 1) / 2;
    gemm_core<2048>(Qp + (size_t)bm * 256 * 2048,
                    Kp + (size_t)bn * 256 * 2048, lds, 32, acc);
    ep_f32(sc, acc, bm * 256, bn * 256, 4096, scale);
  } else {
    const int v = id - 184, bm = v >> 4, bn = v & 15;
    gemm_core<2048>(wvb + (size_t)bm * 256 * 2048,
                    xb + (size_t)bn * 256 * 2048, lds, 32, acc);
    ep_bf16(Vt, acc, bm * 256, bn * 256, 4096);
  }
}

// pv queue: 320 jobs, bm descending (LPT). (bm,bn) split into s=(bm>>2)+1
// K-pieces (<=16u). Piece 0 -> out (f32); pieces 1..3 -> aux1/2/3 (bf16,
// plain writes in dead-sc space); add3 combines.
__global__ __launch_bounds__(512, 2)
void pv_q(const unsigned short* __restrict__ P,
          const unsigned short* __restrict__ Vt, float* __restrict__ out,
          unsigned short* __restrict__ aux1, unsigned short* __restrict__ aux2,
          unsigned short* __restrict__ aux3, int* __restrict__ ctr) {
  __shared__ __align__(16) unsigned short lds[65536];
  __shared__ int sid;
  f32x4 acc[8][4];
  for (;;) {
    if (threadIdx.x == 0) sid = atomicAdd(ctr, 1);
    __syncthreads();
    const int id = sid;
    if (id >= 320) return;
    int rem = id, bm = 15, s = 4;
    for (;;) {
      s = (bm >> 2) + 1;
      const int cnt = 8 * s;
      if (rem < cnt) break;
      rem -= cnt;
      --bm;
    }
    const int bn = rem / s, p = rem % s;
    const int kt = (bm + 1) * 4;
    const int k0 = (kt * p) / s, k1 = (kt * (p + 1)) / s;
    gemm_core<4096>(P + (size_t)bm * 256 * 4096 + (size_t)k0 * 64,
                    Vt + (size_t)bn * 256 * 4096 + (size_t)k0 * 64,
                    lds, k1 - k0, acc);
    if (p == 0)      ep_f32(out,   acc, bm * 256,        bn * 256, 2048, 1.0f);
    else if (p == 1) ep_bf16(aux1, acc, bm * 256 - 1024, bn * 256, 2048);
    else if (p == 2) ep_bf16(aux2, acc, bm * 256 - 2048, bn * 256, 2048);
    else             ep_bf16(aux3, acc, bm * 256 - 3072, bn * 256, 2048);
  }
}

// out rows 1024.. += aux1 (+aux2 rows>=2048) (+aux3 rows>=3072), bf16 partials
__global__ void add3(float* __restrict__ out, const unsigned short* __restrict__ aux1,
                     const unsigned short* __restrict__ aux2,
                     const unsigned short* __restrict__ aux3) {
  const size_t i = ((size_t)blockIdx.x * 256 + threadIdx.x) * 8;  // over 3072*2048
  const int row = 1024 + (int)(i >> 11);
  float* o = out + (size_t)1024 * 2048 + i;
  f32x4 a0 = *(const f32x4*)o;
  f32x4 a1 = *(const f32x4*)(o + 4);
  u16x8 b = *(const u16x8*)(aux1 + i);
#pragma unroll
  for (int k = 0; k < 4; ++k) { a0[k] += bf2f(b[k]); a1[k] += bf2f(b[k + 4]); }
  if (row >= 2048) {
    const size_t j = i - (size_t)1024 * 2048;
    u16x8 c = *(const u16x8*)(aux2 + j);
#pragma unroll
    for (int k = 0; k < 4; ++k) { a0[k] += bf2f(c[k]); a1[k] += bf2f(c[k + 4]); }
  }
  if (row >= 3072) {
    const size_t j = i - (size_t)2048 * 2048;
    u16x8 d = *(const u16x8*)(aux3 + j);
#pragma unroll
    for (int k = 0; k < 4; ++k) { a0[k] += bf2f(d[k]); a1[k] += bf2f(d[k + 4]); }
  }
  *(f32x4*)o = a0;
  *(f32x4*)(o + 4) = a1;
}

// ---------------- causal row softmax: scores f32 -> P bf16 ------------------
__global__ void softmax_causal(const float* __restrict__ Sc,
                               unsigned short* __restrict__ P, int S) {
  const int i = blockIdx.x;
  const int tid = threadIdx.x;
  const int nvalid = i + 1;
  const int pad_end = ((i >> 8) + 1) << 8;   // 256-tile boundary
  const float* row = Sc + (size_t)i * S;

  float v[16];
  float m = -1e30f;
#pragma unroll
  for (int it = 0; it < 16; ++it) {
    const int j = tid + it * 256;
    const float x = (j < nvalid) ? row[j] : -1e30f;
    v[it] = x;
    m = fmaxf(m, x);
  }
#pragma unroll
  for (int d = 1; d < 64; d <<= 1) m = fmaxf(m, __shfl_xor(m, d));
  __shared__ float red_m[4], red_s[4];
  const int lane = tid & 63, wv = tid >> 6;
  if (lane == 0) red_m[wv] = m;
  __syncthreads();
  m = fmaxf(fmaxf(red_m[0], red_m[1]), fmaxf(red_m[2], red_m[3]));

  float s = 0.0f;
#pragma unroll
  for (int it = 0; it < 16; ++it) {
    const int j = tid + it * 256;
    const float e = (j < nvalid) ? __expf(v[it] - m) : 0.0f;
    v[it] = e;
    s += e;
  }
#pragma unroll
  for (int d = 1; d < 64; d <<= 1) s += __shfl_xor(s, d);
  if (lane == 0) red_s[wv] = s;
  __syncthreads();
  s = red_s[0] + red_s[1] + red_s[2] + red_s[3];

  const float inv = 1.0f / s;
  unsigned short* prow = P + (size_t)i * S;
#pragma unroll
  for (int it = 0; it < 16; ++it) {
    const int j = tid + it * 256;
    if (j < pad_end) prow[j] = (j < nvalid) ? f2bf(v[it] * inv) : (unsigned short)0;
  }
}

// ---------------- launch -----------------------------------------------------
extern "C" void kernel_launch(void* const* d_in, const int* in_sizes, int n_in,
                              void* d_out, int out_size, void* d_ws, size_t ws_size,
                              hipStream_t stream) {
  const float* x  = (const float*)d_in[0];
  const float* Wq = (const float*)d_in[1];
  const float* Wk = (const float*)d_in[2];
  const float* Wv = (const float*)d_in[3];
  float* out = (float*)d_out;

  const int S = 4096, D = 2048;
  char* ws = (char*)d_ws;
  const size_t MB = 1u << 20;
  // Workspace (peak 136 MiB + 16 B):
  //   sc   [  0, 64)  f32 scores           live: vt_qkt .. softmax
  //   aux1 [  0, 12)  aux2 [16,24) aux3 [28,32)  bf16 (over dead sc)  pv..add3
  //   xb   [ 64, 80)                       live: cvt .. vt_qkt
  //   wqb  [ 80, 88)  wkb [88,96)          live: cvt .. proj_qk
  //   wvb  [ 96,104)                       live: cvt .. vt_qkt
  //   Q    [104,120)  Kb [120,136)         live: proj_qk .. vt_qkt
  //   Vt   [ 80, 96)  (over wqb/wkb)       live: vt_qkt .. pv
  //   P    [104,136)  (over Q/Kb)          live: softmax .. pv
  //   ctr  [136MB,+16B)
  float*          sc   = (float*)ws;
  unsigned short* aux1 = (unsigned short*)ws;
  unsigned short* aux2 = (unsigned short*)(ws + 16 * MB);
  unsigned short* aux3 = (unsigned short*)(ws + 28 * MB);
  unsigned short* xb   = (unsigned short*)(ws + 64 * MB);
  unsigned short* wqb  = (unsigned short*)(ws + 80 * MB);
  unsigned short* wkb  = (unsigned short*)(ws + 88 * MB);
  unsigned short* wvb  = (unsigned short*)(ws + 96 * MB);
  unsigned short* Q    = (unsigned short*)(ws + 104 * MB);
  unsigned short* Kb   = (unsigned short*)(ws + 120 * MB);
  unsigned short* Vt   = (unsigned short*)(ws + 80 * MB);
  unsigned short* P    = (unsigned short*)(ws + 104 * MB);
  int*            ctr  = (int*)(ws + 136 * MB);

  cvt_all<<<(S * D + 3 * D * D) / (256 * 8), 256, 0, stream>>>(
      x, Wq, Wk, Wv, xb, wqb, wkb, wvb);

  hipMemsetAsync(ctr, 0, 16, stream);
  // zero sc rows 3840..4095 (atomic targets of the 64 QKT chunk jobs)
  hipMemsetAsync(sc + (size_t)3840 * 4096, 0, (size_t)256 * 4096 * 4, stream);

  proj_qk<<<256, 512, 0, stream>>>(xb, wqb, wkb, Q, Kb);

  const float scale = 1.0f / sqrtf((float)D);
  vt_qkt<<<312, 512, 0, stream>>>(Q, Kb, wvb, xb, sc, Vt, scale);

  softmax_causal<<<S, 256, 0, stream>>>(sc, P, S);

  pv_q<<<256, 512, 0, stream>>>(P, Vt, out, aux1, aux2, aux3, ctr);
  add3<<<3072, 256, 0, stream>>>(out, aux1, aux2, aux3);
}